// Round 2
// baseline (41770.901 us; speedup 1.0000x reference)
//
#include <hip/hip_runtime.h>
#include <math.h>

#define CIN 256

// ---------------------------------------------------------------------------
// Generic 3x3 SAME conv, NCHW. Tile: 64 out-channels x 8x8 pixels.
// 128 threads: 8 co-threads x 16 px-threads; each thread 8co x 4px.
// TI = input element type, TA = accumulate/output type, CH = ci chunk.
// ---------------------------------------------------------------------------
template<typename TI, typename TA, int CH, bool RELU>
__global__ __launch_bounds__(128) void conv_tile(
    const TI* __restrict__ in, const float* __restrict__ wgt,
    const float* __restrict__ bias, TA* __restrict__ out,
    int H, int W, int C_out)
{
    const int NCHUNK = CIN / CH;
    const int tilesX = (W + 7) >> 3;
    const int tx = (blockIdx.x % tilesX) * 8;
    const int ty = (blockIdx.x / tilesX) * 8;
    const int b  = blockIdx.y;
    const int co0 = blockIdx.z * 64;
    const int tid = threadIdx.x;
    const int tco = tid >> 4;        // 0..7  -> 8 out-channels each
    const int tpx = tid & 15;        // 0..15 -> 4 pixels each
    const int prow = tpx >> 1;       // 0..7
    const int pcol = (tpx & 1) * 4;  // 0 or 4

    __shared__ __align__(16) TA lw[CH * 9 * 64];  // [ci*9+tap][co]
    __shared__ __align__(16) TA li[CH * 100];     // [ci][10][10]

    TA acc[8][4];
    #pragma unroll
    for (int c = 0; c < 8; ++c)
        #pragma unroll
        for (int j = 0; j < 4; ++j) acc[c][j] = (TA)0;

    const int coLim = min(64, C_out - co0);

    for (int ch = 0; ch < NCHUNK; ++ch) {
        const int ci0 = ch * CH;
        for (int idx = tid; idx < CH * 9 * 64; idx += 128) {
            int co = idx / (CH * 9);
            int r  = idx % (CH * 9);      // ci*9 + tap
            TA v = (TA)0;
            if (co < coLim)
                v = (TA)wgt[(size_t)(co0 + co) * (CIN * 9) + (size_t)ci0 * 9 + r];
            lw[r * 64 + co] = v;
        }
        for (int idx = tid; idx < CH * 100; idx += 128) {
            int ci = idx / 100, r = idx % 100;
            int iy = ty + r / 10 - 1;
            int ix = tx + (r % 10) - 1;
            TA v = (TA)0;
            if (iy >= 0 && iy < H && ix >= 0 && ix < W)
                v = (TA)in[(((size_t)b * CIN + ci0 + ci) * H + iy) * W + ix];
            li[idx] = v;
        }
        __syncthreads();
        #pragma unroll
        for (int ci = 0; ci < CH; ++ci) {
            #pragma unroll
            for (int ky = 0; ky < 3; ++ky) {
                #pragma unroll
                for (int kx = 0; kx < 3; ++kx) {
                    const TA* wp = &lw[(ci * 9 + ky * 3 + kx) * 64 + tco * 8];
                    TA wv[8];
                    #pragma unroll
                    for (int c = 0; c < 8; ++c) wv[c] = wp[c];
                    const TA* ip = &li[ci * 100 + (prow + ky) * 10 + pcol + kx];
                    TA i0 = ip[0], i1 = ip[1], i2 = ip[2], i3 = ip[3];
                    #pragma unroll
                    for (int c = 0; c < 8; ++c) {
                        acc[c][0] += wv[c] * i0;
                        acc[c][1] += wv[c] * i1;
                        acc[c][2] += wv[c] * i2;
                        acc[c][3] += wv[c] * i3;
                    }
                }
            }
        }
        __syncthreads();
    }

    const int oy = ty + prow;
    const int ox = tx + pcol;
    if (oy < H) {
        #pragma unroll
        for (int c = 0; c < 8; ++c) {
            int co = co0 + tco * 8 + c;
            if (co < C_out) {
                TA bv = (TA)bias[co];
                #pragma unroll
                for (int j = 0; j < 4; ++j) {
                    if (ox + j < W) {
                        TA v = acc[c][j] + bv;
                        if (RELU) v = v > (TA)0 ? v : (TA)0;
                        out[(((size_t)b * C_out + co) * H + oy) * W + (ox + j)] = v;
                    }
                }
            }
        }
    }
}

// ---------------------------------------------------------------------------
// Final cls conv (256 -> 720) in fp64, fused sigmoid-max/argmax epilogue.
// One block = one anchor's 80 classes x 8x8 pixels. 320 threads:
// 20 co-threads x 16 px-threads; each thread 4 classes x 4 pixels. CH=4.
// ---------------------------------------------------------------------------
#define CH5 4
__global__ __launch_bounds__(320) void conv_cls5(
    const double* __restrict__ in, const float* __restrict__ wgt,
    const float* __restrict__ bias, float* __restrict__ scores,
    float* __restrict__ cls_id,
    int H, int W, int level_off, int A_total, int b0)
{
    const int tilesX = (W + 7) >> 3;
    const int tx = (blockIdx.x % tilesX) * 8;
    const int ty = (blockIdx.x / tilesX) * 8;
    const int b  = blockIdx.y;           // local batch within chunk
    const int a  = blockIdx.z;           // anchor index 0..8
    const int co0 = a * 80;
    const int tid = threadIdx.x;
    const int tco = tid >> 4;            // 0..19 -> 4 classes each
    const int tpx = tid & 15;
    const int prow = tpx >> 1;
    const int pcol = (tpx & 1) * 4;

    __shared__ __align__(16) double lw[CH5 * 9 * 80];  // [ci*9+tap][80]
    __shared__ __align__(16) double li[CH5 * 100];
    __shared__ double redM[64][20];
    __shared__ int    redA[64][20];

    double acc[4][4];
    #pragma unroll
    for (int c = 0; c < 4; ++c)
        #pragma unroll
        for (int j = 0; j < 4; ++j) acc[c][j] = 0.0;

    for (int ch = 0; ch < CIN / CH5; ++ch) {
        const int ci0 = ch * CH5;
        for (int idx = tid; idx < CH5 * 9 * 80; idx += 320) {
            int co = idx / (CH5 * 9);
            int r  = idx % (CH5 * 9);
            lw[r * 80 + co] =
                (double)wgt[(size_t)(co0 + co) * (CIN * 9) + (size_t)ci0 * 9 + r];
        }
        for (int idx = tid; idx < CH5 * 100; idx += 320) {
            int ci = idx / 100, r = idx % 100;
            int iy = ty + r / 10 - 1;
            int ix = tx + (r % 10) - 1;
            double v = 0.0;
            if (iy >= 0 && iy < H && ix >= 0 && ix < W)
                v = in[(((size_t)b * CIN + ci0 + ci) * H + iy) * W + ix];
            li[idx] = v;
        }
        __syncthreads();
        #pragma unroll
        for (int ci = 0; ci < CH5; ++ci) {
            #pragma unroll
            for (int ky = 0; ky < 3; ++ky) {
                #pragma unroll
                for (int kx = 0; kx < 3; ++kx) {
                    const double* wp = &lw[(ci * 9 + ky * 3 + kx) * 80 + tco * 4];
                    double w0 = wp[0], w1 = wp[1], w2 = wp[2], w3 = wp[3];
                    const double* ip = &li[ci * 100 + (prow + ky) * 10 + pcol + kx];
                    double i0 = ip[0], i1 = ip[1], i2 = ip[2], i3 = ip[3];
                    acc[0][0] += w0 * i0; acc[0][1] += w0 * i1;
                    acc[0][2] += w0 * i2; acc[0][3] += w0 * i3;
                    acc[1][0] += w1 * i0; acc[1][1] += w1 * i1;
                    acc[1][2] += w1 * i2; acc[1][3] += w1 * i3;
                    acc[2][0] += w2 * i0; acc[2][1] += w2 * i1;
                    acc[2][2] += w2 * i2; acc[2][3] += w2 * i3;
                    acc[3][0] += w3 * i0; acc[3][1] += w3 * i1;
                    acc[3][2] += w3 * i2; acc[3][3] += w3 * i3;
                }
            }
        }
        __syncthreads();
    }

    // per-thread max over its 4 classes (ascending -> first max wins ties)
    double bv[4];
    #pragma unroll
    for (int c = 0; c < 4; ++c) bv[c] = (double)bias[co0 + tco * 4 + c];
    #pragma unroll
    for (int j = 0; j < 4; ++j) {
        double m = acc[0][j] + bv[0];
        int am = tco * 4;
        #pragma unroll
        for (int c = 1; c < 4; ++c) {
            double v = acc[c][j] + bv[c];
            if (v > m) { m = v; am = tco * 4 + c; }
        }
        int p = tpx * 4 + j;
        redM[p][tco] = m;
        redA[p][tco] = am;
    }
    __syncthreads();
    if (tid < 64) {
        int p = tid;
        double m = redM[p][0]; int am = redA[p][0];
        #pragma unroll
        for (int t = 1; t < 20; ++t)
            if (redM[p][t] > m) { m = redM[p][t]; am = redA[p][t]; }
        int oy = ty + (p >> 3), ox = tx + (p & 7);
        if (oy < H && ox < W) {
            size_t oi = (size_t)(b0 + b) * A_total + level_off
                      + (size_t)(oy * W + ox) * 9 + a;
            scores[oi] = (float)(1.0 / (1.0 + exp(-m)));
            cls_id[oi] = (float)am;
        }
    }
}

// ---------------------------------------------------------------------------
// Boxes epilogue: analytic anchors + bbox transform from raw reg5 (NCHW, 36ch)
// ---------------------------------------------------------------------------
__global__ void boxes_ep(const float* __restrict__ reg5, float* __restrict__ boxes,
                         int H, int W, int level_off, int A_total, float stride,
                         int b0, int Bc)
{
    int idx = blockIdx.x * 256 + threadIdx.x;   // over Bc*H*W*9
    int total = Bc * H * W * 9;
    if (idx >= total) return;
    int a = idx % 9; int rest = idx / 9;
    int x = rest % W; rest /= W;
    int y = rest % H; int b = rest / H;

    float base = 4.f * stride;
    float scale = exp2f((float)(a % 3) * (1.f / 3.f));
    int ri = a / 3;
    float sr = (ri == 0) ? 0.70710678118654752f : (ri == 1 ? 1.f : 1.41421356237309505f);
    float wa = base * scale / sr;
    float ha = base * scale * sr;
    float cx = (x + 0.5f) * stride, cy = (y + 0.5f) * stride;

    size_t cs = (size_t)H * W;
    const float* rp = reg5 + (((size_t)b * 36 + a * 4) * H + y) * W + x;
    float d0 = rp[0], d1 = rp[cs], d2 = rp[2 * cs], d3 = rp[3 * cs];

    float pcx = cx + d0 * 0.1f * wa;
    float pcy = cy + d1 * 0.1f * ha;
    float pw  = expf(d2 * 0.2f) * wa;
    float ph  = expf(d3 * 0.2f) * ha;

    size_t oi = ((size_t)(b0 + b) * A_total + level_off
               + (size_t)(y * W + x) * 9 + a) * 4;
    boxes[oi + 0] = pcx - 0.5f * pw;
    boxes[oi + 1] = pcy - 0.5f * ph;
    boxes[oi + 2] = pcx + 0.5f * pw;
    boxes[oi + 3] = pcy + 0.5f * ph;
}

// ---------------------------------------------------------------------------
extern "C" void kernel_launch(void* const* d_in, const int* in_sizes, int n_in,
                              void* d_out, int out_size, void* d_ws, size_t ws_size,
                              hipStream_t stream)
{
    const float* feats[5];
    for (int i = 0; i < 5; ++i) feats[i] = (const float*)d_in[i];
    const float* cw[5]; const float* cb[5];
    const float* rw[5]; const float* rb[5];
    for (int i = 0; i < 5; ++i) {
        cw[i] = (const float*)d_in[5 + 2 * i];
        cb[i] = (const float*)d_in[6 + 2 * i];
        rw[i] = (const float*)d_in[15 + 2 * i];
        rb[i] = (const float*)d_in[16 + 2 * i];
    }

    const int A_total = 49104;
    float* scores = (float*)d_out;
    float* cls_id = scores + (size_t)8 * A_total;
    float* boxes  = scores + (size_t)2 * 8 * A_total;

    const int   Hs[5]      = {64, 32, 16, 8, 4};
    const float strides[5] = {8.f, 16.f, 32.f, 64.f, 128.f};
    const int   offs[5]    = {0, 36864, 46080, 48384, 48960};

    // fp64 batch chunk for cls tower: 2 * Bc * 256 * 4096 * 8 bytes of ws
    int Bc = 8;
    while (Bc > 1 && 2ull * Bc * 256 * 4096 * 8 > ws_size) Bc >>= 1;
    double* D0 = (double*)d_ws;
    double* D1 = D0 + (size_t)Bc * 256 * 64 * 64;

    for (int b0 = 0; b0 < 8; b0 += Bc) {
        for (int l = 0; l < 5; ++l) {
            int H = Hs[l], W = Hs[l];
            int tiles = ((W + 7) / 8) * ((H + 7) / 8);
            dim3 g(tiles, Bc, 4);
            const float* fin = feats[l] + (size_t)b0 * CIN * H * W;
            conv_tile<float,  double, 4, true><<<g, 128, 0, stream>>>(fin, cw[0], cb[0], D0, H, W, 256);
            conv_tile<double, double, 4, true><<<g, 128, 0, stream>>>(D0,  cw[1], cb[1], D1, H, W, 256);
            conv_tile<double, double, 4, true><<<g, 128, 0, stream>>>(D1,  cw[2], cb[2], D0, H, W, 256);
            conv_tile<double, double, 4, true><<<g, 128, 0, stream>>>(D0,  cw[3], cb[3], D1, H, W, 256);
            dim3 g5(tiles, Bc, 9);
            conv_cls5<<<g5, 320, 0, stream>>>(D1, cw[4], cb[4], scores, cls_id,
                                              H, W, offs[l], A_total, b0);
        }
    }

    // reg tower in fp32 (boxes tolerate fp32); chunk if ws is small
    int Br = 8;
    while (Br > 1 && 2ull * Br * 256 * 4096 * 4 > ws_size) Br >>= 1;
    float* F0 = (float*)d_ws;
    float* F1 = F0 + (size_t)Br * 256 * 64 * 64;

    for (int b0 = 0; b0 < 8; b0 += Br) {
        for (int l = 0; l < 5; ++l) {
            int H = Hs[l], W = Hs[l];
            int tiles = ((W + 7) / 8) * ((H + 7) / 8);
            dim3 g(tiles, Br, 4);
            const float* fin = feats[l] + (size_t)b0 * CIN * H * W;
            conv_tile<float, float, 8, true><<<g, 128, 0, stream>>>(fin, rw[0], rb[0], F0, H, W, 256);
            conv_tile<float, float, 8, true><<<g, 128, 0, stream>>>(F0,  rw[1], rb[1], F1, H, W, 256);
            conv_tile<float, float, 8, true><<<g, 128, 0, stream>>>(F1,  rw[2], rb[2], F0, H, W, 256);
            conv_tile<float, float, 8, true><<<g, 128, 0, stream>>>(F0,  rw[3], rb[3], F1, H, W, 256);
            dim3 gr(tiles, Br, 1);
            conv_tile<float, float, 8, false><<<gr, 128, 0, stream>>>(F1, rw[4], rb[4], F0, H, W, 36);
            int total = Br * H * W * 9;
            boxes_ep<<<(total + 255) / 256, 256, 0, stream>>>(F0, boxes, H, W,
                                                              offs[l], A_total,
                                                              strides[l], b0, Br);
        }
    }
}

// Round 3
// 27290.170 us; speedup vs baseline: 1.5306x; 1.5306x over previous
//
#include <hip/hip_runtime.h>
#include <math.h>

#define CIN 256
#define TLW 16
#define TLH 8
#define LIS 20   // padded li row stride (16B alignment for f32 and f64)

// ---------------------------------------------------------------------------
// Generic 3x3 SAME conv, NCHW. Tile: 64 out-channels x (8 x 16) pixels.
// 256 threads: 8 co-groups x 32 px-threads; each thread 8co x 4px.
// ---------------------------------------------------------------------------
template<typename TI, typename TA, int CH, bool RELU>
__global__ __launch_bounds__(256) void conv_tile(
    const TI* __restrict__ in, const float* __restrict__ wgt,
    const float* __restrict__ bias, TA* __restrict__ out,
    int H, int W, int C_out)
{
    const int NCH = CIN / CH;
    const int tilesX = (W + TLW - 1) / TLW;
    const int tx = (blockIdx.x % tilesX) * TLW;
    const int ty = (blockIdx.x / tilesX) * TLH;
    const int b  = blockIdx.y;
    const int co0 = blockIdx.z * 64;
    const int tid = threadIdx.x;
    const int tco = (tid >> 5) * 8;       // 8 out-channels per thread
    const int tpx = tid & 31;
    const int prow = tpx >> 2;            // 0..7
    const int pcol = (tpx & 3) * 4;       // 0,4,8,12

    __shared__ __align__(16) TA lw[CH * 9 * 64];      // [ci*9+tap][co]
    __shared__ __align__(16) TA li[CH * 10 * LIS];    // [ci][10][LIS]

    TA acc[8][4];
    #pragma unroll
    for (int c = 0; c < 8; ++c)
        #pragma unroll
        for (int j = 0; j < 4; ++j) acc[c][j] = (TA)0;

    const int coLim = min(64, C_out - co0);

    for (int ch = 0; ch < NCH; ++ch) {
        const int ci0 = ch * CH;
        // weights -> LDS; co fastest => conflict-free LDS writes
        for (int idx = tid; idx < CH * 9 * 64; idx += 256) {
            int r  = idx >> 6;            // ci*9 + tap (chunk-local)
            int co = idx & 63;
            TA v = (TA)0;
            if (co < coLim)
                v = (TA)wgt[(size_t)(co0 + co) * (CIN * 9) + (size_t)ci0 * 9 + r];
            lw[idx] = v;
        }
        // input tile with halo -> LDS (cols fastest => coalesced)
        for (int idx = tid; idx < CH * 10 * LIS; idx += 256) {
            int ci = idx / (10 * LIS);
            int rr = idx % (10 * LIS);
            int row = rr / LIS, col = rr % LIS;
            TA v = (TA)0;
            int iy = ty + row - 1, ix = tx + col - 1;
            if (col < TLW + 2 && iy >= 0 && iy < H && ix >= 0 && ix < W)
                v = (TA)in[(((size_t)b * CIN + ci0 + ci) * H + iy) * W + ix];
            li[idx] = v;
        }
        __syncthreads();
        #pragma unroll
        for (int ci = 0; ci < CH; ++ci) {
            #pragma unroll
            for (int ky = 0; ky < 3; ++ky) {
                const TA* ip = &li[ci * 10 * LIS + (prow + ky) * LIS + pcol];
                TA ir[6];
                #pragma unroll
                for (int t = 0; t < 6; ++t) ir[t] = ip[t];
                #pragma unroll
                for (int kx = 0; kx < 3; ++kx) {
                    const TA* wp = &lw[(ci * 9 + ky * 3 + kx) * 64 + tco];
                    TA wv[8];
                    #pragma unroll
                    for (int c = 0; c < 8; ++c) wv[c] = wp[c];
                    TA x0 = ir[kx], x1 = ir[kx + 1], x2 = ir[kx + 2], x3 = ir[kx + 3];
                    #pragma unroll
                    for (int c = 0; c < 8; ++c) {
                        acc[c][0] += wv[c] * x0;
                        acc[c][1] += wv[c] * x1;
                        acc[c][2] += wv[c] * x2;
                        acc[c][3] += wv[c] * x3;
                    }
                }
            }
        }
        __syncthreads();
    }

    const int oy = ty + prow;
    if (oy < H) {
        #pragma unroll
        for (int c = 0; c < 8; ++c) {
            int co = co0 + tco + c;
            if (co < C_out) {
                TA bv = (TA)bias[co];
                #pragma unroll
                for (int j = 0; j < 4; ++j) {
                    int ox = tx + pcol + j;
                    if (ox < W) {
                        TA v = acc[c][j] + bv;
                        if (RELU) v = v > (TA)0 ? v : (TA)0;
                        out[(((size_t)b * C_out + co) * H + oy) * W + ox] = v;
                    }
                }
            }
        }
    }
}

// ---------------------------------------------------------------------------
// Final cls conv (256 -> 720) in fp64, fused sigmoid-max/argmax epilogue.
// One block = one anchor's 80 classes x (8 x 16) px. 320 threads:
// 20 co-threads x 16 px-threads; each thread 4 classes x 8 pixels.
// ---------------------------------------------------------------------------
#define CH5 8
__global__ __launch_bounds__(320) void conv_cls5(
    const double* __restrict__ in, const float* __restrict__ wgt,
    const float* __restrict__ bias, float* __restrict__ scores,
    float* __restrict__ cls_id,
    int H, int W, int level_off, int A_total, int b0)
{
    const int tilesX = (W + TLW - 1) / TLW;
    const int tx = (blockIdx.x % tilesX) * TLW;
    const int ty = (blockIdx.x / tilesX) * TLH;
    const int b  = blockIdx.y;
    const int a  = blockIdx.z;
    const int co0 = a * 80;
    const int tid = threadIdx.x;
    const int tc  = tid >> 4;            // 0..19 co-thread
    const int tco4 = tc * 4;
    const int tp  = tid & 15;
    const int prow = tp >> 1;            // 0..7
    const int pcol = (tp & 1) * 8;       // 0 or 8

    __shared__ __align__(16) double lw[CH5 * 9 * 80];   // 46.1 KB
    __shared__ __align__(16) double li[CH5 * 10 * LIS]; // 12.8 KB

    double acc[4][8];
    #pragma unroll
    for (int c = 0; c < 4; ++c)
        #pragma unroll
        for (int j = 0; j < 8; ++j) acc[c][j] = 0.0;

    for (int ch = 0; ch < CIN / CH5; ++ch) {
        const int ci0 = ch * CH5;
        for (int idx = tid; idx < CH5 * 9 * 80; idx += 320) {
            int r  = idx / 80;
            int co = idx % 80;
            lw[idx] = (double)wgt[(size_t)(co0 + co) * (CIN * 9)
                                  + (size_t)ci0 * 9 + r];
        }
        for (int idx = tid; idx < CH5 * 10 * LIS; idx += 320) {
            int ci = idx / (10 * LIS);
            int rr = idx % (10 * LIS);
            int row = rr / LIS, col = rr % LIS;
            double v = 0.0;
            int iy = ty + row - 1, ix = tx + col - 1;
            if (col < TLW + 2 && iy >= 0 && iy < H && ix >= 0 && ix < W)
                v = in[(((size_t)b * CIN + ci0 + ci) * H + iy) * W + ix];
            li[idx] = v;
        }
        __syncthreads();
        #pragma unroll
        for (int ci = 0; ci < CH5; ++ci) {
            #pragma unroll
            for (int ky = 0; ky < 3; ++ky) {
                const double* ip = &li[ci * 10 * LIS + (prow + ky) * LIS + pcol];
                double ir[10];
                #pragma unroll
                for (int t = 0; t < 10; ++t) ir[t] = ip[t];
                #pragma unroll
                for (int kx = 0; kx < 3; ++kx) {
                    const double* wp = &lw[(ci * 9 + ky * 3 + kx) * 80 + tco4];
                    double w0 = wp[0], w1 = wp[1], w2 = wp[2], w3 = wp[3];
                    #pragma unroll
                    for (int j = 0; j < 8; ++j) {
                        double x = ir[kx + j];
                        acc[0][j] += w0 * x;
                        acc[1][j] += w1 * x;
                        acc[2][j] += w2 * x;
                        acc[3][j] += w3 * x;
                    }
                }
            }
        }
        __syncthreads();
    }

    // reuse dead lw/li as reduction scratch (after final barrier above)
    double* redM = lw;               // 128*20 doubles = 20.5 KB
    int*    redA = (int*)li;         // 128*20 ints   = 10.2 KB

    double bv[4];
    #pragma unroll
    for (int c = 0; c < 4; ++c) bv[c] = (double)bias[co0 + tco4 + c];
    #pragma unroll
    for (int j = 0; j < 8; ++j) {
        double m = acc[0][j] + bv[0];
        int am = tco4;
        #pragma unroll
        for (int c = 1; c < 4; ++c) {
            double v = acc[c][j] + bv[c];
            if (v > m) { m = v; am = tco4 + c; }
        }
        int p = prow * 16 + pcol + j;
        redM[p * 20 + tc] = m;
        redA[p * 20 + tc] = am;
    }
    __syncthreads();
    if (tid < 128) {
        int p = tid;
        double m = redM[p * 20]; int am = redA[p * 20];
        #pragma unroll
        for (int t = 1; t < 20; ++t)
            if (redM[p * 20 + t] > m) { m = redM[p * 20 + t]; am = redA[p * 20 + t]; }
        int oy = ty + (p >> 4), ox = tx + (p & 15);
        if (oy < H && ox < W) {
            size_t oi = (size_t)(b0 + b) * A_total + level_off
                      + (size_t)(oy * W + ox) * 9 + a;
            scores[oi] = (float)(1.0 / (1.0 + exp(-m)));
            cls_id[oi] = (float)am;
        }
    }
}

// ---------------------------------------------------------------------------
// Boxes epilogue: analytic anchors + bbox transform from raw reg5 (NCHW, 36ch)
// ---------------------------------------------------------------------------
__global__ void boxes_ep(const float* __restrict__ reg5, float* __restrict__ boxes,
                         int H, int W, int level_off, int A_total, float stride,
                         int b0, int Bc)
{
    int idx = blockIdx.x * 256 + threadIdx.x;
    int total = Bc * H * W * 9;
    if (idx >= total) return;
    int a = idx % 9; int rest = idx / 9;
    int x = rest % W; rest /= W;
    int y = rest % H; int b = rest / H;

    float base = 4.f * stride;
    float scale = exp2f((float)(a % 3) * (1.f / 3.f));
    int ri = a / 3;
    float sr = (ri == 0) ? 0.70710678118654752f : (ri == 1 ? 1.f : 1.41421356237309505f);
    float wa = base * scale / sr;
    float ha = base * scale * sr;
    float cx = (x + 0.5f) * stride, cy = (y + 0.5f) * stride;

    size_t cs = (size_t)H * W;
    const float* rp = reg5 + (((size_t)b * 36 + a * 4) * H + y) * W + x;
    float d0 = rp[0], d1 = rp[cs], d2 = rp[2 * cs], d3 = rp[3 * cs];

    float pcx = cx + d0 * 0.1f * wa;
    float pcy = cy + d1 * 0.1f * ha;
    float pw  = expf(d2 * 0.2f) * wa;
    float ph  = expf(d3 * 0.2f) * ha;

    size_t oi = ((size_t)(b0 + b) * A_total + level_off
               + (size_t)(y * W + x) * 9 + a) * 4;
    boxes[oi + 0] = pcx - 0.5f * pw;
    boxes[oi + 1] = pcy - 0.5f * ph;
    boxes[oi + 2] = pcx + 0.5f * pw;
    boxes[oi + 3] = pcy + 0.5f * ph;
}

// ---------------------------------------------------------------------------
extern "C" void kernel_launch(void* const* d_in, const int* in_sizes, int n_in,
                              void* d_out, int out_size, void* d_ws, size_t ws_size,
                              hipStream_t stream)
{
    const float* feats[5];
    for (int i = 0; i < 5; ++i) feats[i] = (const float*)d_in[i];
    const float* cw[5]; const float* cb[5];
    const float* rw[5]; const float* rb[5];
    for (int i = 0; i < 5; ++i) {
        cw[i] = (const float*)d_in[5 + 2 * i];
        cb[i] = (const float*)d_in[6 + 2 * i];
        rw[i] = (const float*)d_in[15 + 2 * i];
        rb[i] = (const float*)d_in[16 + 2 * i];
    }

    const int A_total = 49104;
    float* scores = (float*)d_out;
    float* cls_id = scores + (size_t)8 * A_total;
    float* boxes  = scores + (size_t)2 * 8 * A_total;

    const int   Hs[5]      = {64, 32, 16, 8, 4};
    const float strides[5] = {8.f, 16.f, 32.f, 64.f, 128.f};
    const int   offs[5]    = {0, 36864, 46080, 48384, 48960};

    // ---------------- cls tower (fp64), per-level adaptive batch chunk -----
    for (int l = 0; l < 5; ++l) {
        int H = Hs[l], W = Hs[l];
        size_t perb = (size_t)CIN * H * W;                 // elems per batch
        int Bc = 8;
        while (Bc > 1 && 2ull * Bc * perb * sizeof(double) > ws_size) Bc >>= 1;
        double* D0 = (double*)d_ws;
        double* D1 = D0 + (size_t)Bc * perb;
        int tiles = ((W + TLW - 1) / TLW) * ((H + TLH - 1) / TLH);
        for (int b0 = 0; b0 < 8; b0 += Bc) {
            dim3 g(tiles, Bc, 4);
            const float* fin = feats[l] + (size_t)b0 * perb;
            conv_tile<float,  double, 8, true><<<g, 256, 0, stream>>>(fin, cw[0], cb[0], D0, H, W, 256);
            conv_tile<double, double, 8, true><<<g, 256, 0, stream>>>(D0,  cw[1], cb[1], D1, H, W, 256);
            conv_tile<double, double, 8, true><<<g, 256, 0, stream>>>(D1,  cw[2], cb[2], D0, H, W, 256);
            conv_tile<double, double, 8, true><<<g, 256, 0, stream>>>(D0,  cw[3], cb[3], D1, H, W, 256);
            dim3 g5(tiles, Bc, 9);
            conv_cls5<<<g5, 320, 0, stream>>>(D1, cw[4], cb[4], scores, cls_id,
                                              H, W, offs[l], A_total, b0);
        }
    }

    // ---------------- reg tower (fp32) -------------------------------------
    for (int l = 0; l < 5; ++l) {
        int H = Hs[l], W = Hs[l];
        size_t perb = (size_t)CIN * H * W;
        int Br = 8;
        while (Br > 1 && 2ull * Br * perb * sizeof(float) > ws_size) Br >>= 1;
        float* F0 = (float*)d_ws;
        float* F1 = F0 + (size_t)Br * perb;
        int tiles = ((W + TLW - 1) / TLW) * ((H + TLH - 1) / TLH);
        for (int b0 = 0; b0 < 8; b0 += Br) {
            dim3 g(tiles, Br, 4);
            const float* fin = feats[l] + (size_t)b0 * perb;
            conv_tile<float, float, 8, true><<<g, 256, 0, stream>>>(fin, rw[0], rb[0], F0, H, W, 256);
            conv_tile<float, float, 8, true><<<g, 256, 0, stream>>>(F0,  rw[1], rb[1], F1, H, W, 256);
            conv_tile<float, float, 8, true><<<g, 256, 0, stream>>>(F1,  rw[2], rb[2], F0, H, W, 256);
            conv_tile<float, float, 8, true><<<g, 256, 0, stream>>>(F0,  rw[3], rb[3], F1, H, W, 256);
            dim3 gr(tiles, Br, 1);
            conv_tile<float, float, 8, false><<<gr, 256, 0, stream>>>(F1, rw[4], rb[4], F0, H, W, 36);
            int total = Br * H * W * 9;
            boxes_ep<<<(total + 255) / 256, 256, 0, stream>>>(F0, boxes, H, W,
                                                              offs[l], A_total,
                                                              strides[l], b0, Br);
        }
    }
}

// Round 4
// 25006.032 us; speedup vs baseline: 1.6704x; 1.0913x over previous
//
#include <hip/hip_runtime.h>
#include <math.h>

#define CIN 256
#define TLW 16
#define TLH 8
#define LIS 22   // padded li row stride: 22 elems -> b128 reads hit all 32 banks

// ---------------------------------------------------------------------------
// Generic 3x3 SAME conv, NCHW. Tile: 64 out-channels x (8 x 16) pixels.
// 256 threads: 8 co-groups x 32 px-threads; each thread 8co x 4px.
// ---------------------------------------------------------------------------
template<typename TI, typename TA, int CH, bool RELU>
__global__ __launch_bounds__(256, 2) void conv_tile(
    const TI* __restrict__ in, const float* __restrict__ wgt,
    const float* __restrict__ bias, TA* __restrict__ out,
    int H, int W, int C_out)
{
    const int NCH = CIN / CH;
    const int tilesX = (W + TLW - 1) / TLW;
    const int tx = (blockIdx.x % tilesX) * TLW;
    const int ty = (blockIdx.x / tilesX) * TLH;
    const int b  = blockIdx.y;
    const int co0 = blockIdx.z * 64;
    const int tid = threadIdx.x;
    const int tco = (tid >> 5) * 8;       // 8 out-channels per thread
    const int tpx = tid & 31;
    const int prow = tpx >> 2;            // 0..7
    const int pcol = (tpx & 3) * 4;       // 0,4,8,12

    __shared__ __align__(16) TA lw[CH * 9 * 64];      // [ci*9+tap][co]
    __shared__ __align__(16) TA li[CH * 10 * LIS];    // [ci][10][LIS]

    TA acc[8][4];
    #pragma unroll
    for (int c = 0; c < 8; ++c)
        #pragma unroll
        for (int j = 0; j < 4; ++j) acc[c][j] = (TA)0;

    const int coLim = min(64, C_out - co0);

    for (int ch = 0; ch < NCH; ++ch) {
        const int ci0 = ch * CH;
        // weights -> LDS; linear idx => conflict-free LDS writes (co fastest)
        for (int idx = tid; idx < CH * 9 * 64; idx += 256) {
            int r  = idx >> 6;            // ci*9 + tap (chunk-local)
            int co = idx & 63;
            TA v = (TA)0;
            if (co < coLim)
                v = (TA)wgt[(size_t)(co0 + co) * (CIN * 9) + (size_t)ci0 * 9 + r];
            lw[idx] = v;
        }
        // input tile with halo -> LDS (cols fastest => coalesced global reads)
        for (int idx = tid; idx < CH * 10 * LIS; idx += 256) {
            int ci = idx / (10 * LIS);
            int rr = idx % (10 * LIS);
            int row = rr / LIS, col = rr % LIS;
            TA v = (TA)0;
            int iy = ty + row - 1, ix = tx + col - 1;
            if (col < TLW + 2 && iy >= 0 && iy < H && ix >= 0 && ix < W)
                v = (TA)in[(((size_t)b * CIN + ci0 + ci) * H + iy) * W + ix];
            li[idx] = v;
        }
        __syncthreads();
        #pragma unroll
        for (int ci = 0; ci < CH; ++ci) {
            #pragma unroll
            for (int ky = 0; ky < 3; ++ky) {
                const TA* ip = &li[ci * 10 * LIS + (prow + ky) * LIS + pcol];
                TA ir[6];
                #pragma unroll
                for (int t = 0; t < 6; ++t) ir[t] = ip[t];
                #pragma unroll
                for (int kx = 0; kx < 3; ++kx) {
                    const TA* wp = &lw[(ci * 9 + ky * 3 + kx) * 64 + tco];
                    TA wv[8];
                    #pragma unroll
                    for (int c = 0; c < 8; ++c) wv[c] = wp[c];
                    TA x0 = ir[kx], x1 = ir[kx + 1], x2 = ir[kx + 2], x3 = ir[kx + 3];
                    #pragma unroll
                    for (int c = 0; c < 8; ++c) {
                        acc[c][0] += wv[c] * x0;
                        acc[c][1] += wv[c] * x1;
                        acc[c][2] += wv[c] * x2;
                        acc[c][3] += wv[c] * x3;
                    }
                }
            }
        }
        __syncthreads();
    }

    const int oy = ty + prow;
    if (oy < H) {
        #pragma unroll
        for (int c = 0; c < 8; ++c) {
            int co = co0 + tco + c;
            if (co < C_out) {
                TA bv = (TA)bias[co];
                #pragma unroll
                for (int j = 0; j < 4; ++j) {
                    int ox = tx + pcol + j;
                    if (ox < W) {
                        TA v = acc[c][j] + bv;
                        if (RELU) v = v > (TA)0 ? v : (TA)0;
                        out[(((size_t)b * C_out + co) * H + oy) * W + ox] = v;
                    }
                }
            }
        }
    }
}

// ---------------------------------------------------------------------------
// Final cls conv (256 -> 720) in fp64, fused sigmoid-max/argmax epilogue.
// One block = one anchor's 80 classes x (8 x 16) px. 256 threads:
// 8 co-groups x 32 px-threads; each thread 10 classes x 4 pixels.
// ---------------------------------------------------------------------------
#define CH5 8
__global__ __launch_bounds__(256, 2) void conv_cls5(
    const double* __restrict__ in, const float* __restrict__ wgt,
    const float* __restrict__ bias, float* __restrict__ scores,
    float* __restrict__ cls_id,
    int H, int W, int level_off, int A_total, int b0)
{
    const int tilesX = (W + TLW - 1) / TLW;
    const int tx = (blockIdx.x % tilesX) * TLW;
    const int ty = (blockIdx.x / tilesX) * TLH;
    const int b  = blockIdx.y;
    const int a  = blockIdx.z;
    const int co0 = a * 80;
    const int tid = threadIdx.x;
    const int cog = tid >> 5;            // 0..7
    const int tco = cog * 10;            // 10 classes per thread
    const int tpx = tid & 31;
    const int prow = tpx >> 2;           // 0..7
    const int pcol = (tpx & 3) * 4;      // 0,4,8,12

    __shared__ __align__(16) double lw[CH5 * 9 * 80];   // 46.1 KB
    __shared__ __align__(16) double li[CH5 * 10 * LIS]; // 13.8 KB

    double acc[10][4];
    #pragma unroll
    for (int c = 0; c < 10; ++c)
        #pragma unroll
        for (int j = 0; j < 4; ++j) acc[c][j] = 0.0;

    for (int ch = 0; ch < CIN / CH5; ++ch) {
        const int ci0 = ch * CH5;
        for (int idx = tid; idx < CH5 * 9 * 80; idx += 256) {
            int r  = idx / 80;
            int co = idx % 80;
            lw[idx] = (double)wgt[(size_t)(co0 + co) * (CIN * 9)
                                  + (size_t)ci0 * 9 + r];
        }
        for (int idx = tid; idx < CH5 * 10 * LIS; idx += 256) {
            int ci = idx / (10 * LIS);
            int rr = idx % (10 * LIS);
            int row = rr / LIS, col = rr % LIS;
            double v = 0.0;
            int iy = ty + row - 1, ix = tx + col - 1;
            if (col < TLW + 2 && iy >= 0 && iy < H && ix >= 0 && ix < W)
                v = in[(((size_t)b * CIN + ci0 + ci) * H + iy) * W + ix];
            li[idx] = v;
        }
        __syncthreads();
        #pragma unroll
        for (int ci = 0; ci < CH5; ++ci) {
            #pragma unroll
            for (int ky = 0; ky < 3; ++ky) {
                const double* ip = &li[ci * 10 * LIS + (prow + ky) * LIS + pcol];
                double ir[6];
                #pragma unroll
                for (int t = 0; t < 6; ++t) ir[t] = ip[t];
                #pragma unroll
                for (int kx = 0; kx < 3; ++kx) {
                    const double* wp = &lw[(ci * 9 + ky * 3 + kx) * 80 + tco];
                    double wv[10];
                    #pragma unroll
                    for (int c = 0; c < 10; ++c) wv[c] = wp[c];
                    double x0 = ir[kx], x1 = ir[kx + 1], x2 = ir[kx + 2], x3 = ir[kx + 3];
                    #pragma unroll
                    for (int c = 0; c < 10; ++c) {
                        acc[c][0] += wv[c] * x0;
                        acc[c][1] += wv[c] * x1;
                        acc[c][2] += wv[c] * x2;
                        acc[c][3] += wv[c] * x3;
                    }
                }
            }
        }
        __syncthreads();
    }

    // reuse dead lw/li as reduction scratch
    double* redM = lw;               // 128 px * 8 cog doubles = 8 KB
    int*    redA = (int*)li;         // 128 px * 8 cog ints   = 4 KB

    // per-thread max over its 10 classes (ascending c -> first max wins ties)
    #pragma unroll
    for (int j = 0; j < 4; ++j) {
        double m = acc[0][j] + (double)bias[co0 + tco];
        int am = tco;
        #pragma unroll
        for (int c = 1; c < 10; ++c) {
            double v = acc[c][j] + (double)bias[co0 + tco + c];
            if (v > m) { m = v; am = tco + c; }
        }
        int p = prow * 16 + pcol + j;
        redM[p * 8 + cog] = m;
        redA[p * 8 + cog] = am;
    }
    __syncthreads();
    if (tid < 128) {
        int p = tid;
        double m = redM[p * 8]; int am = redA[p * 8];
        #pragma unroll
        for (int t = 1; t < 8; ++t)
            if (redM[p * 8 + t] > m) { m = redM[p * 8 + t]; am = redA[p * 8 + t]; }
        int oy = ty + (p >> 4), ox = tx + (p & 15);
        if (oy < H && ox < W) {
            size_t oi = (size_t)(b0 + b) * A_total + level_off
                      + (size_t)(oy * W + ox) * 9 + a;
            scores[oi] = (float)(1.0 / (1.0 + exp(-m)));
            cls_id[oi] = (float)am;
        }
    }
}

// ---------------------------------------------------------------------------
// Boxes epilogue: analytic anchors + bbox transform from raw reg5 (NCHW, 36ch)
// ---------------------------------------------------------------------------
__global__ void boxes_ep(const float* __restrict__ reg5, float* __restrict__ boxes,
                         int H, int W, int level_off, int A_total, float stride,
                         int b0, int Bc)
{
    int idx = blockIdx.x * 256 + threadIdx.x;
    int total = Bc * H * W * 9;
    if (idx >= total) return;
    int a = idx % 9; int rest = idx / 9;
    int x = rest % W; rest /= W;
    int y = rest % H; int b = rest / H;

    float base = 4.f * stride;
    float scale = exp2f((float)(a % 3) * (1.f / 3.f));
    int ri = a / 3;
    float sr = (ri == 0) ? 0.70710678118654752f : (ri == 1 ? 1.f : 1.41421356237309505f);
    float wa = base * scale / sr;
    float ha = base * scale * sr;
    float cx = (x + 0.5f) * stride, cy = (y + 0.5f) * stride;

    size_t cs = (size_t)H * W;
    const float* rp = reg5 + (((size_t)b * 36 + a * 4) * H + y) * W + x;
    float d0 = rp[0], d1 = rp[cs], d2 = rp[2 * cs], d3 = rp[3 * cs];

    float pcx = cx + d0 * 0.1f * wa;
    float pcy = cy + d1 * 0.1f * ha;
    float pw  = expf(d2 * 0.2f) * wa;
    float ph  = expf(d3 * 0.2f) * ha;

    size_t oi = ((size_t)(b0 + b) * A_total + level_off
               + (size_t)(y * W + x) * 9 + a) * 4;
    boxes[oi + 0] = pcx - 0.5f * pw;
    boxes[oi + 1] = pcy - 0.5f * ph;
    boxes[oi + 2] = pcx + 0.5f * pw;
    boxes[oi + 3] = pcy + 0.5f * ph;
}

// ---------------------------------------------------------------------------
extern "C" void kernel_launch(void* const* d_in, const int* in_sizes, int n_in,
                              void* d_out, int out_size, void* d_ws, size_t ws_size,
                              hipStream_t stream)
{
    const float* feats[5];
    for (int i = 0; i < 5; ++i) feats[i] = (const float*)d_in[i];
    const float* cw[5]; const float* cb[5];
    const float* rw[5]; const float* rb[5];
    for (int i = 0; i < 5; ++i) {
        cw[i] = (const float*)d_in[5 + 2 * i];
        cb[i] = (const float*)d_in[6 + 2 * i];
        rw[i] = (const float*)d_in[15 + 2 * i];
        rb[i] = (const float*)d_in[16 + 2 * i];
    }

    const int A_total = 49104;
    float* scores = (float*)d_out;
    float* cls_id = scores + (size_t)8 * A_total;
    float* boxes  = scores + (size_t)2 * 8 * A_total;

    const int   Hs[5]      = {64, 32, 16, 8, 4};
    const float strides[5] = {8.f, 16.f, 32.f, 64.f, 128.f};
    const int   offs[5]    = {0, 36864, 46080, 48384, 48960};

    // ---------------- cls tower (fp64), per-level adaptive batch chunk -----
    for (int l = 0; l < 5; ++l) {
        int H = Hs[l], W = Hs[l];
        size_t perb = (size_t)CIN * H * W;
        int Bc = 8;
        while (Bc > 1 && 2ull * Bc * perb * sizeof(double) > ws_size) Bc >>= 1;
        double* D0 = (double*)d_ws;
        double* D1 = D0 + (size_t)Bc * perb;
        int tiles = ((W + TLW - 1) / TLW) * ((H + TLH - 1) / TLH);
        for (int b0 = 0; b0 < 8; b0 += Bc) {
            dim3 g(tiles, Bc, 4);
            const float* fin = feats[l] + (size_t)b0 * perb;
            conv_tile<float,  double, 8, true><<<g, 256, 0, stream>>>(fin, cw[0], cb[0], D0, H, W, 256);
            conv_tile<double, double, 8, true><<<g, 256, 0, stream>>>(D0,  cw[1], cb[1], D1, H, W, 256);
            conv_tile<double, double, 8, true><<<g, 256, 0, stream>>>(D1,  cw[2], cb[2], D0, H, W, 256);
            conv_tile<double, double, 8, true><<<g, 256, 0, stream>>>(D0,  cw[3], cb[3], D1, H, W, 256);
            dim3 g5(tiles, Bc, 9);
            conv_cls5<<<g5, 256, 0, stream>>>(D1, cw[4], cb[4], scores, cls_id,
                                              H, W, offs[l], A_total, b0);
        }
    }

    // ---------------- reg tower (fp32) -------------------------------------
    for (int l = 0; l < 5; ++l) {
        int H = Hs[l], W = Hs[l];
        size_t perb = (size_t)CIN * H * W;
        int Br = 8;
        while (Br > 1 && 2ull * Br * perb * sizeof(float) > ws_size) Br >>= 1;
        float* F0 = (float*)d_ws;
        float* F1 = F0 + (size_t)Br * perb;
        int tiles = ((W + TLW - 1) / TLW) * ((H + TLH - 1) / TLH);
        for (int b0 = 0; b0 < 8; b0 += Br) {
            dim3 g(tiles, Br, 4);
            const float* fin = feats[l] + (size_t)b0 * perb;
            conv_tile<float, float, 8, true><<<g, 256, 0, stream>>>(fin, rw[0], rb[0], F0, H, W, 256);
            conv_tile<float, float, 8, true><<<g, 256, 0, stream>>>(F0,  rw[1], rb[1], F1, H, W, 256);
            conv_tile<float, float, 8, true><<<g, 256, 0, stream>>>(F1,  rw[2], rb[2], F0, H, W, 256);
            conv_tile<float, float, 8, true><<<g, 256, 0, stream>>>(F0,  rw[3], rb[3], F1, H, W, 256);
            dim3 gr(tiles, Br, 1);
            conv_tile<float, float, 8, false><<<gr, 256, 0, stream>>>(F1, rw[4], rb[4], F0, H, W, 36);
            int total = Br * H * W * 9;
            boxes_ep<<<(total + 255) / 256, 256, 0, stream>>>(F0, boxes, H, W,
                                                              offs[l], A_total,
                                                              strides[l], b0, Br);
        }
    }
}